// Round 6
// baseline (309.858 us; speedup 1.0000x reference)
//
#include <hip/hip_runtime.h>
#include <stdint.h>

typedef float f32x4 __attribute__((ext_vector_type(4)));
typedef __bf16 bf16x8 __attribute__((ext_vector_type(8)));
typedef unsigned short ushortx8 __attribute__((ext_vector_type(8)));

#define D_DIM 512
#define KGC 10
#define NCLU 8
#define BATCH 32
#define WPOS 250
#define WPAD 256
#define KDIM 3584   // 512*7
#define MROWS 522   // 512 feat + 10 assign
#define MPAD 528    // Y rows per batch
#define MBIG 544    // rows computed by fused gemm (34*16)
#define KSPLIT 2
#define KCHUNK 1792 // KDIM / KSPLIT
#define NS 28       // KCHUNK / 64
#define NTILES 128  // 32 batches * 4 n-tiles of 64

__device__ __forceinline__ float bf2f(unsigned short u) {
  union { unsigned int i; float f; } v; v.i = ((unsigned int)u) << 16; return v.f;
}
__device__ __forceinline__ unsigned short f2bf(float f) {
  union { float f; unsigned int i; } v; v.f = f;
  unsigned int r = v.i + 0x7FFFu + ((v.i >> 16) & 1u);
  return (unsigned short)(r >> 16);
}

__device__ __forceinline__ void load_lds16(const void* g, void* l) {
  __builtin_amdgcn_global_load_lds(
      (const __attribute__((address_space(1))) void*)g,
      (__attribute__((address_space(3))) void*)l, 16, 0, 0);
}

// ---------------- prep: Wcat(bf16) rows 0..543 = [feat_w ; assign_w ; zeros], bcat fp32 ----------------
__global__ void prep_kernel(const float* __restrict__ fw,
                            const float* __restrict__ fb,
                            const float* __restrict__ aw,
                            const float* __restrict__ ab,
                            unsigned short* __restrict__ Wcat,
                            float* __restrict__ bcat) {
  int r = blockIdx.x;
  unsigned short* dst = Wcat + (size_t)r * KDIM;
  const float* src = (r < D_DIM) ? (fw + (size_t)r * KDIM)
                   : (r < MROWS) ? (aw + (size_t)(r - D_DIM) * KDIM)
                                 : nullptr;
  for (int i = threadIdx.x; i < KDIM / 4; i += 256) {
    unsigned short o0 = 0, o1 = 0, o2 = 0, o3 = 0;
    if (src) {
      float4 v = ((const float4*)src)[i];
      o0 = f2bf(v.x); o1 = f2bf(v.y); o2 = f2bf(v.z); o3 = f2bf(v.w);
    }
    ushort4 o; o.x = o0; o.y = o1; o.z = o2; o.w = o3;
    ((ushort4*)dst)[i] = o;
  }
  if (threadIdx.x == 0)
    bcat[r] = r < D_DIM ? fb[r] : (r < MROWS ? ab[r - D_DIM] : 0.f);
}

// ---------------- pipelined fused GEMM: partial C[544m x 64n] over a K-half -------------------------
// 512 thr, grid (128 ntiles, 2 ksplit) = 256 blocks = 1/CU. Double-buffered LDS:
// W-DMA(st+2) issued after barrier(st) -> a full compute step in flight before its drain.
// x register-loads run 2 steps ahead. One barrier per step.
__global__ __launch_bounds__(512, 2) void gemm_fused(
    const float* __restrict__ x, const unsigned short* __restrict__ Wcat,
    float* __restrict__ P) {
  __shared__ __align__(16) unsigned short Wl[2][MBIG * 64];  // 2 x 69632 B, swizzled
  __shared__ __align__(16) unsigned short Xl[2][64 * 64];    // 2 x  8192 B, swizzled
  const int tid = threadIdx.x;
  const int nt = blockIdx.x, sp = blockIdx.y;
  const int b = nt >> 2, n0 = (nt & 3) * 64;
  const int lane = tid & 63, wv = tid >> 6;   // 8 waves
  const int fr = lane & 15, kg = lane >> 4;
  const int sx = fr & 7;
  const int mh = (wv & 1) * 272;              // wave's m-half (17 frags of 16)
  const int nq = wv >> 1;                     // wave's n-quarter (16 n)
  const int nloc = tid & 63, kb = tid >> 6;   // staging role: (n, 16B k-block)
  const int nglob = n0 + nloc;
  const bool okn = nglob < WPOS;
  const float* xb = x + (size_t)b * KDIM * WPOS + nglob;
  const int kbase = sp * KCHUNK;

  float xr[2][8];
  auto loadx = [&](int st, float* dst) {
    int k0 = kbase + st * 64 + kb * 8;
#pragma unroll
    for (int e = 0; e < 8; e++)
      dst[e] = okn ? xb[(size_t)(k0 + e) * WPOS] : 0.f;
  };
  auto dma_w = [&](int buf, int st) {
    int kst = kbase + st * 64;
#pragma unroll
    for (int it = 0; it < 9; it++) {
      int s = it * 512 + tid;
      if (s < MBIG * 8) {
        int row = s >> 3, p = s & 7;
        int blk = p ^ (row & 7);
        load_lds16(Wcat + (size_t)row * KDIM + kst + blk * 8, &Wl[buf][s * 8]);
      }
    }
  };
  auto write_x = [&](int buf, const float* src) {
    ushortx8 pk;
#pragma unroll
    for (int e = 0; e < 8; e++) pk[e] = f2bf(src[e]);
    *(ushortx8*)&Xl[buf][nloc * 64 + (kb ^ (nloc & 7)) * 8] = pk;
  };

  f32x4 acc[17];
  const f32x4 zero = {0.f, 0.f, 0.f, 0.f};
#pragma unroll
  for (int f = 0; f < 17; f++) acc[f] = zero;

  // prologue
  loadx(0, xr[0]);
  loadx(1, xr[1]);
  dma_w(0, 0);
  write_x(0, xr[0]);
  loadx(2, xr[0]);
  __syncthreads();          // Wl[0], Xl[0] ready (one-time exposed DMA drain)
  dma_w(1, 1);              // in flight during compute(0)

  for (int st = 0; st < NS; st++) {
    const int cur = st & 1, nxt = cur ^ 1;
    if (st + 1 < NS) write_x(nxt, xr[nxt]);   // X(st+1); slot (st+1)&1 == nxt
    if (st + 3 < NS) loadx(st + 3, xr[nxt]);  // refill slot; covered by compute(st)
#pragma unroll
    for (int ks = 0; ks < 2; ks++) {
      const int off = ((ks * 4 + kg) ^ sx) * 8;
      bf16x8 bfr = *(const bf16x8*)&Xl[cur][(nq * 16 + fr) * 64 + off];
#pragma unroll
      for (int f = 0; f < 17; f++) {
        bf16x8 af = *(const bf16x8*)&Wl[cur][(mh + f * 16 + fr) * 64 + off];
        acc[f] = __builtin_amdgcn_mfma_f32_16x16x32_bf16(af, bfr, acc[f], 0, 0, 0);
      }
    }
    __syncthreads();                          // drains W-DMA(st+1) (issued a full step ago)
    if (st + 2 < NS) dma_w(cur, st + 2);      // into the buffer compute(st) just released
  }

  // store partials. C/D: col = lane&15 (n), row = kg*4 + r (m within frag)
  float* Pb = P + (size_t)(sp * NTILES + nt) * (MBIG * 64);
  const int n = nq * 16 + fr;
#pragma unroll
  for (int f = 0; f < 17; f++) {
    const int m = mh + f * 16 + kg * 4;
#pragma unroll
    for (int r = 0; r < 4; r++)
      Pb[(size_t)(m + r) * 64 + n] = acc[f][r];
  }
}

// ---------------- reduce: Y[b][m][n](bf16) = relu_if_feat( sum_sp P + bias ) ----------------
__global__ __launch_bounds__(256) void reduce_kernel(
    const float* __restrict__ P, const float* __restrict__ bcat,
    unsigned short* __restrict__ Y) {
  const int nt = blockIdx.x, mg = blockIdx.y;
  const int t = threadIdx.x;
  const int m = mg * 32 + (t >> 3);
  const int nl = (t & 7) * 8;
  if (m >= MPAD) return;
  const size_t base = (size_t)nt * (MBIG * 64) + (size_t)m * 64 + nl;
  const size_t spstr = (size_t)NTILES * (MBIG * 64);
  float s[8];
#pragma unroll
  for (int e = 0; e < 8; e++) s[e] = 0.f;
#pragma unroll
  for (int sp = 0; sp < KSPLIT; sp++) {
    const float* p = P + sp * spstr + base;
    float4 a = *(const float4*)p;
    float4 c = *(const float4*)(p + 4);
    s[0] += a.x; s[1] += a.y; s[2] += a.z; s[3] += a.w;
    s[4] += c.x; s[5] += c.y; s[6] += c.z; s[7] += c.w;
  }
  float bias = bcat[m];
  ushortx8 o;
#pragma unroll
  for (int e = 0; e < 8; e++) {
    float v = s[e] + bias;
    if (m < D_DIM) v = fmaxf(v, 0.f);
    o[e] = f2bf(v);
  }
  const int bb = nt >> 2, c0 = (nt & 3) * 64 + nl;
  *(ushortx8*)&Y[(size_t)bb * MPAD * WPAD + (size_t)m * WPAD + c0] = o;
}

// ---------------- epilogue: softmax, agg, subtract centroids*s_sum, L2-normalize ----------------
__global__ __launch_bounds__(256) void epi_kernel(
    const unsigned short* __restrict__ Y, const float* __restrict__ cent,
    float* __restrict__ out) {
  __shared__ float soft[WPAD];
  __shared__ float red[4];
  const int b = blockIdx.x >> 3, k = blockIdx.x & 7;
  const int tid = threadIdx.x;
  const unsigned short* Yb = Y + (size_t)b * MPAD * WPAD;

  float sv = 0.f;
  if (tid < WPOS) {
    float lg[KGC];
    float mx = -1e30f;
#pragma unroll
    for (int j = 0; j < KGC; j++) {
      lg[j] = bf2f(Yb[(size_t)(D_DIM + j) * WPAD + tid]);
      mx = fmaxf(mx, lg[j]);
    }
    float s = 0.f, ek = 0.f;
#pragma unroll
    for (int j = 0; j < KGC; j++) {
      float e = __expf(lg[j] - mx);
      s += e;
      if (j == k) ek = e;
    }
    sv = ek / s;
  }
  soft[tid] = sv;
  __syncthreads();

  float v = sv;
#pragma unroll
  for (int o = 32; o > 0; o >>= 1) v += __shfl_down(v, o, 64);
  if ((tid & 63) == 0) red[tid >> 6] = v;
  __syncthreads();
  float ssum = red[0] + red[1] + red[2] + red[3];

  float a0 = 0.f, a1 = 0.f;
  const unsigned short* row0 = Yb + (size_t)tid * WPAD;
  const unsigned short* row1 = Yb + (size_t)(tid + 256) * WPAD;
  for (int w = 0; w < WPAD; w += 8) {
    ushortx8 f0 = *(const ushortx8*)(row0 + w);
    ushortx8 f1 = *(const ushortx8*)(row1 + w);
#pragma unroll
    for (int u = 0; u < 8; u++) {
      float s = soft[w + u];
      a0 += bf2f(f0[u]) * s;
      a1 += bf2f(f1[u]) * s;
    }
  }
  float c0 = a0 - cent[(size_t)tid * KGC + k] * ssum;
  float c1 = a1 - cent[(size_t)(tid + 256) * KGC + k] * ssum;

  __syncthreads();
  float q = c0 * c0 + c1 * c1;
#pragma unroll
  for (int o = 32; o > 0; o >>= 1) q += __shfl_down(q, o, 64);
  if ((tid & 63) == 0) red[tid >> 6] = q;
  __syncthreads();
  float norm = sqrtf(red[0] + red[1] + red[2] + red[3]);
  float inv = 1.f / fmaxf(norm, 1e-12f);

  float* ob = out + (size_t)b * (NCLU * D_DIM) + (size_t)k * D_DIM;
  ob[tid] = c0 * inv;
  ob[tid + 256] = c1 * inv;
}

extern "C" void kernel_launch(void* const* d_in, const int* in_sizes, int n_in,
                              void* d_out, int out_size, void* d_ws, size_t ws_size,
                              hipStream_t stream) {
  const float* x  = (const float*)d_in[0];
  const float* fw = (const float*)d_in[1];
  const float* fb = (const float*)d_in[2];
  const float* aw = (const float*)d_in[3];
  const float* ab = (const float*)d_in[4];
  const float* ce = (const float*)d_in[5];
  float* out = (float*)d_out;
  char* ws = (char*)d_ws;

  const size_t WC_BYTES = (size_t)MBIG * KDIM * 2;                  //  3,899,392
  const size_t BC_BYTES = 4096;
  const size_t P_BYTES  = (size_t)KSPLIT * NTILES * MBIG * 64 * 4;  // 35,651,584
  unsigned short* Wc = (unsigned short*)(ws);
  float*          bc = (float*)(ws + WC_BYTES);
  float*          P  = (float*)(ws + WC_BYTES + BC_BYTES);
  unsigned short* Yv = (unsigned short*)(ws + WC_BYTES + BC_BYTES + P_BYTES);
  // total ws use ~48 MB

  prep_kernel<<<MBIG, 256, 0, stream>>>(fw, fb, aw, ab, Wc, bc);
  gemm_fused<<<dim3(NTILES, KSPLIT), 512, 0, stream>>>(x, Wc, P);
  reduce_kernel<<<dim3(NTILES, 17), 256, 0, stream>>>(P, bc, Yv);
  epi_kernel<<<BATCH * NCLU, 256, 0, stream>>>(Yv, ce, out);
}

// Round 8
// 236.026 us; speedup vs baseline: 1.3128x; 1.3128x over previous
//
#include <hip/hip_runtime.h>
#include <stdint.h>

typedef float f32x4 __attribute__((ext_vector_type(4)));
typedef __bf16 bf16x8 __attribute__((ext_vector_type(8)));
typedef unsigned short ushortx8 __attribute__((ext_vector_type(8)));

#define D_DIM 512
#define KGC 10
#define NCLU 8
#define BATCH 32
#define WPOS 250
#define WPAD 256
#define KDIM 3584   // 512*7
#define MROWS 522   // 512 feat + 10 assign
#define MPAD 528    // Y rows per batch
#define MBIG 544    // 2 * 272
#define MH 272      // m-half rows per block
#define BN 128
#define KSPLIT 4
#define KCHUNK 896  // KDIM / KSPLIT
#define NS 14       // KCHUNK / 64
#define NT 64       // n-tiles of 128 (N = 8192)

__device__ __forceinline__ float bf2f(unsigned short u) {
  union { unsigned int i; float f; } v; v.i = ((unsigned int)u) << 16; return v.f;
}
__device__ __forceinline__ unsigned short f2bf(float f) {
  union { float f; unsigned int i; } v; v.f = f;
  unsigned int r = v.i + 0x7FFFu + ((v.i >> 16) & 1u);
  return (unsigned short)(r >> 16);
}

__device__ __forceinline__ void load_lds16(const void* g, void* l) {
  __builtin_amdgcn_global_load_lds(
      (const __attribute__((address_space(1))) void*)g,
      (__attribute__((address_space(3))) void*)l, 16, 0, 0);
}

// ---------------- prep: Wcat(bf16) rows 0..543 = [feat_w ; assign_w ; zeros], bcat fp32 ----------------
__global__ void prep_kernel(const float* __restrict__ fw,
                            const float* __restrict__ fb,
                            const float* __restrict__ aw,
                            const float* __restrict__ ab,
                            unsigned short* __restrict__ Wcat,
                            float* __restrict__ bcat) {
  int r = blockIdx.x;
  unsigned short* dst = Wcat + (size_t)r * KDIM;
  const float* src = (r < D_DIM) ? (fw + (size_t)r * KDIM)
                   : (r < MROWS) ? (aw + (size_t)(r - D_DIM) * KDIM)
                                 : nullptr;
  for (int i = threadIdx.x; i < KDIM / 4; i += 256) {
    unsigned short o0 = 0, o1 = 0, o2 = 0, o3 = 0;
    if (src) {
      float4 v = ((const float4*)src)[i];
      o0 = f2bf(v.x); o1 = f2bf(v.y); o2 = f2bf(v.z); o3 = f2bf(v.w);
    }
    ushort4 o; o.x = o0; o.y = o1; o.z = o2; o.w = o3;
    ((ushort4*)dst)[i] = o;
  }
  if (threadIdx.x == 0)
    bcat[r] = r < D_DIM ? fb[r] : (r < MROWS ? ab[r - D_DIM] : 0.f);
}

// ---------------- fused GEMM: partial C[272m x 128n] over a K-quarter ------------------------------
// 512 thr, grid (64 nt, 2 mh, 4 sp) = 512 blocks = 2/CU. Single-buffer 2-barrier K-loop;
// W via swizzled lds-dma (34.8 KB/step); X from x directly (fp32 loads -> bf16 -> ds_write_b128).
__global__ __launch_bounds__(512, 4) void gemm_fused(
    const float* __restrict__ x, const unsigned short* __restrict__ Wcat,
    float* __restrict__ P) {
  __shared__ __align__(16) unsigned short Wl[MH * 64];  // 34,816 B swizzled
  __shared__ __align__(16) unsigned short Xl[BN * 64];  // 16,384 B swizzled
  const int tid = threadIdx.x;
  const int nt = blockIdx.x, mh = blockIdx.y, sp = blockIdx.z;
  const int lane = tid & 63, wv = tid >> 6;     // 8 waves
  const int fr = lane & 15, kg = lane >> 4;
  const int sx = fr & 7;
  const int nloc = tid & 127, oc = tid >> 7;    // staging: row nloc, octets oc & oc+4
  const int nglob = nt * BN + nloc;
  const int b = nglob >> 8, ncol = nglob & 255;
  const bool okn = ncol < WPOS;
  const float* xb = x + (size_t)b * KDIM * WPOS + ncol;
  const int kbase = sp * KCHUNK;
  const unsigned short* Wg = Wcat + (size_t)mh * MH * KDIM + kbase;

  float xr[16];
  auto loadx = [&](int st) {
#pragma unroll
    for (int pass = 0; pass < 2; pass++) {
      int k0 = kbase + st * 64 + (oc + 4 * pass) * 8;
#pragma unroll
      for (int e = 0; e < 8; e++)
        xr[pass * 8 + e] = okn ? xb[(size_t)(k0 + e) * WPOS] : 0.f;
    }
  };

  f32x4 acc[17];
  const f32x4 zero = {0.f, 0.f, 0.f, 0.f};
#pragma unroll
  for (int f = 0; f < 17; f++) acc[f] = zero;

  loadx(0);

  for (int st = 0; st < NS; st++) {
    __syncthreads();
    // W lds-dma: 272 rows x 8 octets = 2176 slots
#pragma unroll
    for (int it = 0; it < 5; it++) {
      int s = it * 512 + tid;
      if (s < MH * 8) {
        int row = s >> 3, p = s & 7;
        int blk = p ^ (row & 7);
        load_lds16(Wg + (size_t)row * KDIM + st * 64 + blk * 8, &Wl[s * 8]);
      }
    }
    // commit X (loaded last iter), swizzled
#pragma unroll
    for (int pass = 0; pass < 2; pass++) {
      int oct = oc + 4 * pass;
      ushortx8 pk;
#pragma unroll
      for (int e = 0; e < 8; e++) pk[e] = f2bf(xr[pass * 8 + e]);
      *(ushortx8*)&Xl[nloc * 64 + (oct ^ (nloc & 7)) * 8] = pk;
    }
    __syncthreads();
    if (st + 1 < NS) loadx(st + 1);   // latency covered by MFMA loop
#pragma unroll
    for (int ks = 0; ks < 2; ks++) {
      const int off = ((ks * 4 + kg) ^ sx) * 8;
      bf16x8 bfr = *(const bf16x8*)&Xl[(wv * 16 + fr) * 64 + off];
#pragma unroll
      for (int f = 0; f < 17; f++) {
        bf16x8 af = *(const bf16x8*)&Wl[(f * 16 + fr) * 64 + off];
        acc[f] = __builtin_amdgcn_mfma_f32_16x16x32_bf16(af, bfr, acc[f], 0, 0, 0);
      }
    }
  }

  // store partials. C/D: col = lane&15 (n), row = kg*4 + r (m within frag)
  float* Pb = P + (size_t)(((sp * 2 + mh) * NT) + nt) * (MH * BN);
  const int n = wv * 16 + fr;
#pragma unroll
  for (int f = 0; f < 17; f++) {
    const int m = f * 16 + kg * 4;
#pragma unroll
    for (int r = 0; r < 4; r++)
      Pb[(size_t)(m + r) * BN + n] = acc[f][r];
  }
}

// ---------------- reduce: Y[b][m][n](bf16) = relu_if_feat( sum_sp P + bias ) ----------------
// block = 16 m-rows x 16 n-octets (full 128 cols); grid (64 nt, 34 m-groups)
__global__ __launch_bounds__(256) void reduce_kernel(
    const float* __restrict__ P, const float* __restrict__ bcat,
    unsigned short* __restrict__ Y) {
  const int nt = blockIdx.x, mg = blockIdx.y;
  const int t = threadIdx.x;
  const int m = mg * 16 + (t >> 4);          // 0..543
  const int nl = (t & 15) * 8;               // n-octet within 128
  if (m >= MPAD) return;
  const int mh = m >= MH, ml = m - mh * MH;
  const size_t slice = (size_t)MH * BN;
  const size_t base = (size_t)ml * BN + nl;
  float s[8];
#pragma unroll
  for (int e = 0; e < 8; e++) s[e] = 0.f;
#pragma unroll
  for (int sp = 0; sp < KSPLIT; sp++) {
    const float* p = P + ((size_t)((sp * 2 + mh) * NT) + nt) * slice + base;
    float4 a = *(const float4*)p;
    float4 c = *(const float4*)(p + 4);
    s[0] += a.x; s[1] += a.y; s[2] += a.z; s[3] += a.w;
    s[4] += c.x; s[5] += c.y; s[6] += c.z; s[7] += c.w;
  }
  float bias = bcat[m];
  ushortx8 o;
#pragma unroll
  for (int e = 0; e < 8; e++) {
    float v = s[e] + bias;
    if (m < D_DIM) v = fmaxf(v, 0.f);
    o[e] = f2bf(v);
  }
  const int nglob = nt * BN + nl;
  const int bb = nglob >> 8, col = nglob & 255;
  *(ushortx8*)&Y[(size_t)bb * MPAD * WPAD + (size_t)m * WPAD + col] = o;
}

// ---------------- epilogue: softmax, agg, subtract centroids*s_sum, L2-normalize ----------------
__global__ __launch_bounds__(256) void epi_kernel(
    const unsigned short* __restrict__ Y, const float* __restrict__ cent,
    float* __restrict__ out) {
  __shared__ float soft[WPAD];
  __shared__ float red[4];
  const int b = blockIdx.x >> 3, k = blockIdx.x & 7;
  const int tid = threadIdx.x;
  const unsigned short* Yb = Y + (size_t)b * MPAD * WPAD;

  float sv = 0.f;
  if (tid < WPOS) {
    float lg[KGC];
    float mx = -1e30f;
#pragma unroll
    for (int j = 0; j < KGC; j++) {
      lg[j] = bf2f(Yb[(size_t)(D_DIM + j) * WPAD + tid]);
      mx = fmaxf(mx, lg[j]);
    }
    float s = 0.f, ek = 0.f;
#pragma unroll
    for (int j = 0; j < KGC; j++) {
      float e = __expf(lg[j] - mx);
      s += e;
      if (j == k) ek = e;
    }
    sv = ek / s;
  }
  soft[tid] = sv;
  __syncthreads();

  float v = sv;
#pragma unroll
  for (int o = 32; o > 0; o >>= 1) v += __shfl_down(v, o, 64);
  if ((tid & 63) == 0) red[tid >> 6] = v;
  __syncthreads();
  float ssum = red[0] + red[1] + red[2] + red[3];

  float a0 = 0.f, a1 = 0.f;
  const unsigned short* row0 = Yb + (size_t)tid * WPAD;
  const unsigned short* row1 = Yb + (size_t)(tid + 256) * WPAD;
  for (int w = 0; w < WPAD; w += 8) {
    ushortx8 f0 = *(const ushortx8*)(row0 + w);
    ushortx8 f1 = *(const ushortx8*)(row1 + w);
#pragma unroll
    for (int u = 0; u < 8; u++) {
      float s = soft[w + u];
      a0 += bf2f(f0[u]) * s;
      a1 += bf2f(f1[u]) * s;
    }
  }
  float c0 = a0 - cent[(size_t)tid * KGC + k] * ssum;
  float c1 = a1 - cent[(size_t)(tid + 256) * KGC + k] * ssum;

  __syncthreads();
  float q = c0 * c0 + c1 * c1;
#pragma unroll
  for (int o = 32; o > 0; o >>= 1) q += __shfl_down(q, o, 64);
  if ((tid & 63) == 0) red[tid >> 6] = q;
  __syncthreads();
  float norm = sqrtf(red[0] + red[1] + red[2] + red[3]);
  float inv = 1.f / fmaxf(norm, 1e-12f);

  float* ob = out + (size_t)b * (NCLU * D_DIM) + (size_t)k * D_DIM;
  ob[tid] = c0 * inv;
  ob[tid + 256] = c1 * inv;
}

extern "C" void kernel_launch(void* const* d_in, const int* in_sizes, int n_in,
                              void* d_out, int out_size, void* d_ws, size_t ws_size,
                              hipStream_t stream) {
  const float* x  = (const float*)d_in[0];
  const float* fw = (const float*)d_in[1];
  const float* fb = (const float*)d_in[2];
  const float* aw = (const float*)d_in[3];
  const float* ab = (const float*)d_in[4];
  const float* ce = (const float*)d_in[5];
  float* out = (float*)d_out;
  char* ws = (char*)d_ws;

  const size_t WC_BYTES = (size_t)MBIG * KDIM * 2;                      //  3,899,392
  const size_t BC_BYTES = 4096;
  const size_t P_BYTES  = (size_t)KSPLIT * 2 * NT * MH * BN * 4;        // 71,303,168
  unsigned short* Wc = (unsigned short*)(ws);
  float*          bc = (float*)(ws + WC_BYTES);
  float*          P  = (float*)(ws + WC_BYTES + BC_BYTES);
  unsigned short* Yv = (unsigned short*)(ws + WC_BYTES + BC_BYTES + P_BYTES);
  // total ws use ~84 MB

  prep_kernel<<<MBIG, 256, 0, stream>>>(fw, fb, aw, ab, Wc, bc);
  gemm_fused<<<dim3(NT, 2, KSPLIT), 512, 0, stream>>>(x, Wc, P);
  reduce_kernel<<<dim3(NT, 34), 256, 0, stream>>>(P, bc, Yv);
  epi_kernel<<<BATCH * NCLU, 256, 0, stream>>>(Yv, ce, out);
}